// Round 1
// baseline (157.812 us; speedup 1.0000x reference)
//
#include <hip/hip_runtime.h>

// Problem constants (fixed by setup_inputs)
#define NN 100000          // nodes
#define NE 1200000         // edges
#define IND 6              // in dim
#define HID 64             // hidden
#define CAP1 256           // max edges with dst==agent (E[X]=12, P(X>64)~1e-30)
#define CAPS 257           // max unique level-0 nodes (agent + srcs)

// Workspace layout, in 4-byte elements (ws is int*/float* aliased):
#define OFF_DEGC   0                       // int[NN]  degree counts (excl. self-loop)
#define OFF_AGENT  (NN)                    // int      agent node id
#define OFF_CNT1   (NN + 1)                // int      # edges with dst==agent
#define OFF_M      (NN + 2)                // int      # unique S nodes
#define OFF_EDGEA  (NN + 4)                // int[CAP1] src of agent-edges
#define OFF_SLOT   (OFF_EDGEA + CAP1)      // int[CAP1] slot in S per agent-edge
#define OFF_S      (OFF_SLOT + CAP1)       // int[CAPS] unique node list, S[0]=agent
#define OFF_NORMA  (OFF_S + CAPS)          // float[CAP1] norm per agent-edge
#define OFF_H1PRE  (OFF_NORMA + CAP1)      // float[CAPS*HID] L1 message accum
#define OFF_H1     (OFF_H1PRE + CAPS*HID)  // float[CAPS*HID] L1 activations
#define ZERO_END   OFF_H1                  // zero [0, ZERO_END)

// K0: zero workspace prefix (skipping the agent slot) + find agent node
__global__ void k0_init(const float* __restrict__ x, int* __restrict__ wsI) {
    int i = blockIdx.x * blockDim.x + threadIdx.x;
    if (i < ZERO_END && i != OFF_AGENT) wsI[i] = 0;
    if (i < NN) {
        if (x[i * IND + 1] == 1.0f) wsI[OFF_AGENT] = i;  // exactly one match
    }
}

// K1: degree scatter + collect edges into agent
__global__ void k1_deg(const int* __restrict__ src, const int* __restrict__ dst,
                       int* __restrict__ wsI) {
    int e = blockIdx.x * blockDim.x + threadIdx.x;
    if (e >= NE) return;
    int d = dst[e];
    atomicAdd(&wsI[OFF_DEGC + d], 1);
    int ag = wsI[OFF_AGENT];
    if (d == ag) {
        int s = src[e];
        int i = atomicAdd(&wsI[OFF_CNT1], 1);
        if (i < CAP1) wsI[OFF_EDGEA + i] = s;
    }
}

// K2: serial dedup of agent-edge sources -> S; precompute per-edge slot + norm
__global__ void k2_dedup(int* __restrict__ wsI, float* __restrict__ wsF) {
    if (threadIdx.x != 0 || blockIdx.x != 0) return;
    int ag = wsI[OFF_AGENT];
    int c = wsI[OFF_CNT1]; if (c > CAP1) c = CAP1;
    int* S = wsI + OFF_S;
    int m = 0;
    S[m++] = ag;  // slot 0 = agent
    float dinv_ag = rsqrtf((float)(wsI[OFF_DEGC + ag] + 1));
    for (int i = 0; i < c; ++i) {
        int s = wsI[OFF_EDGEA + i];
        int p = -1;
        for (int j = 0; j < m; ++j) if (S[j] == s) { p = j; break; }
        if (p < 0) { p = m; S[m++] = s; }
        wsI[OFF_SLOT + i] = p;
        wsF[OFF_NORMA + i] = rsqrtf((float)(wsI[OFF_DEGC + s] + 1)) * dinv_ag;
    }
    wsI[OFF_M] = m;
}

// K3: edge pass 2 — accumulate L1 messages for dst in S
__global__ void k3_msgs(const int* __restrict__ src, const int* __restrict__ dst,
                        const float* __restrict__ x, const float* __restrict__ W1,
                        int* __restrict__ wsI, float* __restrict__ wsF) {
    __shared__ int sS[CAPS];
    __shared__ int smv;
    __shared__ float sW1[IND * HID];
    int t = threadIdx.x;
    if (t == 0) smv = wsI[OFF_M];
    for (int i = t; i < IND * HID; i += blockDim.x) sW1[i] = W1[i];
    __syncthreads();
    int m = smv;
    for (int i = t; i < m; i += blockDim.x) sS[i] = wsI[OFF_S + i];
    __syncthreads();

    int e = blockIdx.x * blockDim.x + t;
    if (e >= NE) return;
    int d = dst[e];
    int p = -1;
    for (int j = 0; j < m; ++j) if (sS[j] == d) { p = j; break; }
    if (p < 0) return;

    int s = src[e];
    float norm = rsqrtf((float)(wsI[OFF_DEGC + s] + 1)) *
                 rsqrtf((float)(wsI[OFF_DEGC + d] + 1));
    float xv[IND];
#pragma unroll
    for (int i = 0; i < IND; ++i) xv[i] = x[s * IND + i];
    float* hp = wsF + OFF_H1PRE + p * HID;
    for (int k = 0; k < HID; ++k) {
        float acc = 0.f;
#pragma unroll
        for (int i = 0; i < IND; ++i) acc += xv[i] * sW1[i * HID + k];
        atomicAdd(&hp[k], norm * acc);
    }
}

// K4: finalize h1 for S nodes: + self-loop term + bias, ReLU
__global__ void k4_h1(const float* __restrict__ x, const float* __restrict__ W1,
                      const float* __restrict__ b1,
                      int* __restrict__ wsI, float* __restrict__ wsF) {
    int b = blockIdx.x;
    if (b >= wsI[OFF_M]) return;
    int node = wsI[OFF_S + b];
    int k = threadIdx.x;  // HID threads
    float acc = 0.f;
#pragma unroll
    for (int i = 0; i < IND; ++i) acc += x[node * IND + i] * W1[i * HID + k];
    float deg = (float)(wsI[OFF_DEGC + node] + 1);
    float v = wsF[OFF_H1PRE + b * HID + k] + acc / deg + b1[k];
    wsF[OFF_H1 + b * HID + k] = fmaxf(v, 0.f);
}

// K5: L2 aggregation at agent + W2 + heads
__global__ void k5_head(const float* __restrict__ W2, const float* __restrict__ b2,
                        const float* __restrict__ Wp, const float* __restrict__ bp,
                        const float* __restrict__ Wv, const float* __restrict__ bv,
                        int* __restrict__ wsI, float* __restrict__ wsF,
                        float* __restrict__ out) {
    __shared__ float z[HID];
    __shared__ float h2[HID];
    int k = threadIdx.x;  // HID threads
    int ag = wsI[OFF_AGENT];
    int c = wsI[OFF_CNT1]; if (c > CAP1) c = CAP1;
    float degag = (float)(wsI[OFF_DEGC + ag] + 1);
    // z = sum_e norm_e * h1[slot_e] + h1[agent]/deg_agent  (agent is slot 0)
    float zk = wsF[OFF_H1 + 0 * HID + k] / degag;
    for (int i = 0; i < c; ++i) {
        int p = wsI[OFF_SLOT + i];
        zk += wsF[OFF_NORMA + i] * wsF[OFF_H1 + p * HID + k];
    }
    z[k] = zk;
    __syncthreads();
    float acc = b2[k];
    for (int j = 0; j < HID; ++j) acc += z[j] * W2[j * HID + k];
    h2[k] = fmaxf(acc, 0.f);
    __syncthreads();
    if (k < 4) {
        float a = bp[k];
        for (int j = 0; j < HID; ++j) a += h2[j] * Wp[j * 4 + k];
        out[k] = a;
    } else if (k == 4) {
        float a = bv[0];
        for (int j = 0; j < HID; ++j) a += h2[j] * Wv[j];
        out[4] = a;
    }
}

extern "C" void kernel_launch(void* const* d_in, const int* in_sizes, int n_in,
                              void* d_out, int out_size, void* d_ws, size_t ws_size,
                              hipStream_t stream) {
    const float* x   = (const float*)d_in[0];
    const int*   ei  = (const int*)d_in[1];   // [2, NE] int32 per harness convention
    const float* W1  = (const float*)d_in[2];
    const float* b1  = (const float*)d_in[3];
    const float* W2  = (const float*)d_in[4];
    const float* b2  = (const float*)d_in[5];
    const float* Wp  = (const float*)d_in[6];
    const float* bp  = (const float*)d_in[7];
    const float* Wv  = (const float*)d_in[8];
    const float* bv  = (const float*)d_in[9];
    const int* srcp = ei;
    const int* dstp = ei + NE;
    int*   wsI = (int*)d_ws;
    float* wsF = (float*)d_ws;
    float* out = (float*)d_out;

    int zb = (ZERO_END + 255) / 256;
    hipLaunchKernelGGL(k0_init, dim3(zb), dim3(256), 0, stream, x, wsI);
    int eb = (NE + 255) / 256;
    hipLaunchKernelGGL(k1_deg, dim3(eb), dim3(256), 0, stream, srcp, dstp, wsI);
    hipLaunchKernelGGL(k2_dedup, dim3(1), dim3(64), 0, stream, wsI, wsF);
    hipLaunchKernelGGL(k3_msgs, dim3(eb), dim3(256), 0, stream, srcp, dstp, x, W1, wsI, wsF);
    hipLaunchKernelGGL(k4_h1, dim3(CAPS), dim3(HID), 0, stream, x, W1, b1, wsI, wsF);
    hipLaunchKernelGGL(k5_head, dim3(1), dim3(HID), 0, stream, W2, b2, Wp, bp, Wv, bv, wsI, wsF, out);
}